// Round 14
// baseline (189.025 us; speedup 1.0000x reference)
//
#include <hip/hip_runtime.h>
#include <hip/hip_bf16.h>
#include <stdint.h>

#define N_ROWS 4096
#define DIM    2048
#define NT     (DIM / 64)   // 32 K-tiles of BK=64
#define EPSF   1e-12f

typedef __bf16 bf16x8 __attribute__((ext_vector_type(8)));
typedef float  f32x4  __attribute__((ext_vector_type(4)));

typedef __attribute__((address_space(1))) void gv_t;
typedef __attribute__((address_space(3))) void lv_t;

__device__ __forceinline__ void gload_lds16(const void* g, void* l) {
    // async global->LDS, 16B/lane; LDS dest = wave-uniform base + lane*16
    __builtin_amdgcn_global_load_lds((gv_t*)g, (lv_t*)l, 16, 0, 0);
}

// round-to-nearest-even f32 -> bf16 bits
__device__ __forceinline__ unsigned f2bf(float f) {
    unsigned u = __float_as_uint(f);
    return (u + 0x7FFFu + ((u >> 16) & 1u)) >> 16;
}

// ---------------------------------------------------------------------------
// Kernel 1: f32 -> bf16 convert, row sum-of-squares, init per-row atoms.
// Wave-per-row: 2048 blocks x 4 waves; lane reads 8 x float4 (grid-stride in
// row), pure shfl reduce - no LDS, no syncthreads (G11).
// ---------------------------------------------------------------------------
__global__ __launch_bounds__(256) void prep_kernel(
    const float* __restrict__ m1, const float* __restrict__ m2,
    unsigned short* __restrict__ abf, unsigned short* __restrict__ bbf,
    float* __restrict__ sq1, float* __restrict__ sq2,
    unsigned* __restrict__ ap_bits, unsigned* __restrict__ an_bits) {
    const int w    = threadIdx.x >> 6;
    const int lane = threadIdx.x & 63;
    const int r_all = blockIdx.x * 4 + w;        // 0..8191
    const bool isB = r_all >= N_ROWS;
    const int r = isB ? r_all - N_ROWS : r_all;
    const float* src = (isB ? m2 : m1) + (size_t)r * DIM;
    unsigned short* dst = (isB ? bbf : abf) + (size_t)r * DIM;

    const float4* s4 = (const float4*)src;       // 512 float4 per row
    float acc = 0.f;
#pragma unroll
    for (int k = 0; k < 8; ++k) {
        float4 v = s4[lane + 64 * k];
        acc += v.x*v.x + v.y*v.y + v.z*v.z + v.w*v.w;
        uint2 p;
        p.x = f2bf(v.x) | (f2bf(v.y) << 16);
        p.y = f2bf(v.z) | (f2bf(v.w) << 16);
        *(uint2*)(dst + (lane + 64 * k) * 4) = p;
    }
    for (int s = 32; s > 0; s >>= 1) acc += __shfl_down(acc, s);
    if (lane == 0) {
        (isB ? sq2 : sq1)[r] = acc;
        if (!isB) {
            ap_bits[r] = 0u;           // dist > 0, so 0.0f works as -inf for max
            an_bits[r] = 0x7f800000u;  // +inf
        }
    }
}

// ---------------------------------------------------------------------------
// Kernel 2: fused bf16 MFMA GEMM (A·B^T) + distance + masked max/min + atomics.
// 8-phase counted-vmcnt (T3+T4+T5+T1) + T2 XOR-swizzle (round-13: conflicts=0).
// This round: t-loop hand-unrolled x2 via k_tile<CUR> so the LDS buffer index
// is COMPILE-TIME (kills per-phase base-select + address recompute VALU).
// Sync structure (barriers, vmcnt ledger, setprio) unchanged from round 13.
// ---------------------------------------------------------------------------
#define STAGE_A(buf, c, kt1) gload_lds16(                                        \
        A + (size_t)(brow + (c) * 64 + srow) * DIM + (kt1) + scol,               \
        &As[buf][((c) * 64 + w * 8) * 64])
#define STAGE_B(buf, c, kt1) gload_lds16(                                        \
        B + (size_t)(bcol + (c) * 64 + srow) * DIM + (kt1) + scol,               \
        &Bs[buf][((c) * 64 + w * 8) * 64])
#define LDA(buf, m, kk) (*(const bf16x8*)&As[buf][(wr * 128 + (m) * 16 + l15) * 64 + (((kk) * 32 + lhi * 8) ^ swz8)])
#define LDB(buf, n, kk) (*(const bf16x8*)&Bs[buf][(wc * 64 + (n) * 16 + l15) * 64 + (((kk) * 32 + lhi * 8) ^ swz8)])
#define BAR() asm volatile("s_barrier" ::: "memory")
#define MFMA(a, b, c) __builtin_amdgcn_mfma_f32_16x16x32_bf16((a), (b), (c), 0, 0, 0)

template<int CUR>
__device__ __forceinline__ void k_tile(
    int t,
    unsigned short (&As)[2][256 * 64], unsigned short (&Bs)[2][256 * 64],
    f32x4 (&acc)[8][4],
    const unsigned short* __restrict__ A, const unsigned short* __restrict__ B,
    int brow, int bcol, int srow, int scol, int w,
    int wr, int wc, int l15, int lhi, int swz8) {
    constexpr int NXT = CUR ^ 1;
    const int  kt1  = (t + 1) * 64;
    const bool more = (t + 1 < NT);
    bf16x8 af[4][2], bn[4][2];

    // ---- phase 1: A rows m0-3 + B cols n0-1; stage next B0,B1 ----
#pragma unroll
    for (int m = 0; m < 4; ++m) { af[m][0] = LDA(CUR, m, 0); af[m][1] = LDA(CUR, m, 1); }
#pragma unroll
    for (int n = 0; n < 2; ++n) { bn[n][0] = LDB(CUR, n, 0); bn[n][1] = LDB(CUR, n, 1); }
    if (more) { STAGE_B(NXT, 0, kt1); STAGE_B(NXT, 1, kt1); }
    BAR();
    __builtin_amdgcn_s_setprio(1);
#pragma unroll
    for (int m = 0; m < 4; ++m)
#pragma unroll
        for (int n = 0; n < 2; ++n) {
            acc[m][n] = MFMA(af[m][0], bn[n][0], acc[m][n]);
            acc[m][n] = MFMA(af[m][1], bn[n][1], acc[m][n]);
        }
    __builtin_amdgcn_s_setprio(0);
    BAR();

    // ---- phase 2: B cols n2-3; stage next B2,B3; counted wait ----
#pragma unroll
    for (int n = 0; n < 2; ++n) { bn[n + 2][0] = LDB(CUR, n + 2, 0); bn[n + 2][1] = LDB(CUR, n + 2, 1); }
    if (more) { STAGE_B(NXT, 2, kt1); STAGE_B(NXT, 3, kt1); }
    if (t == NT - 1) { asm volatile("s_waitcnt vmcnt(0)" ::: "memory"); }
    else             { asm volatile("s_waitcnt vmcnt(4)" ::: "memory"); }  // retire this tile's A1,A3 (read in ph3)
    BAR();
    __builtin_amdgcn_s_setprio(1);
#pragma unroll
    for (int m = 0; m < 4; ++m)
#pragma unroll
        for (int n = 0; n < 2; ++n) {
            acc[m][n + 2] = MFMA(af[m][0], bn[n + 2][0], acc[m][n + 2]);
            acc[m][n + 2] = MFMA(af[m][1], bn[n + 2][1], acc[m][n + 2]);
        }
    __builtin_amdgcn_s_setprio(0);
    BAR();

    // ---- phase 3: A rows m4-7; stage next A0,A2 ----
#pragma unroll
    for (int m = 0; m < 4; ++m) { af[m][0] = LDA(CUR, m + 4, 0); af[m][1] = LDA(CUR, m + 4, 1); }
    if (more) { STAGE_A(NXT, 0, kt1); STAGE_A(NXT, 2, kt1); }
    BAR();
    __builtin_amdgcn_s_setprio(1);
#pragma unroll
    for (int m = 0; m < 4; ++m)
#pragma unroll
        for (int n = 0; n < 2; ++n) {
            acc[m + 4][n] = MFMA(af[m][0], bn[n][0], acc[m + 4][n]);
            acc[m + 4][n] = MFMA(af[m][1], bn[n][1], acc[m + 4][n]);
        }
    __builtin_amdgcn_s_setprio(0);
    BAR();

    // ---- phase 4: no reads; stage next A1,A3; counted wait for next ph1 ----
    if (more) {
        STAGE_A(NXT, 1, kt1); STAGE_A(NXT, 3, kt1);
        asm volatile("s_waitcnt vmcnt(2)" ::: "memory");  // next tile's B0-3,A0,A2 landed; A1,A3 stay in flight
    }
    BAR();
    __builtin_amdgcn_s_setprio(1);
#pragma unroll
    for (int m = 0; m < 4; ++m)
#pragma unroll
        for (int n = 0; n < 2; ++n) {
            acc[m + 4][n + 2] = MFMA(af[m][0], bn[n + 2][0], acc[m + 4][n + 2]);
            acc[m + 4][n + 2] = MFMA(af[m][1], bn[n + 2][1], acc[m + 4][n + 2]);
        }
    __builtin_amdgcn_s_setprio(0);
    BAR();
}

__global__ __launch_bounds__(512) void dist_gemm_kernel(
    const unsigned short* __restrict__ A, const unsigned short* __restrict__ B,
    const float* __restrict__ sq1, const float* __restrict__ sq2,
    const int* __restrict__ tgt,
    unsigned* __restrict__ ap_bits, unsigned* __restrict__ an_bits) {
    __shared__ unsigned short As[2][256 * 64];   // 64 KB
    __shared__ unsigned short Bs[2][256 * 64];   // 64 KB

    const int tid  = threadIdx.x;
    const int w    = tid >> 6;            // wave 0..7
    const int lane = tid & 63;
    const int wr   = w >> 2, wc = w & 3;  // wave grid 2x4; wave owns 128x64 of C
    const int l15  = lane & 15, lhi = lane >> 4;
    const int swz8 = (l15 & 7) * 8;       // read-side XOR key (elements)

    // bijective XCD swizzle over the 16x16 grid (256 blocks, 256 % 8 == 0)
    const int bid  = blockIdx.y * 16 + blockIdx.x;
    const int swz  = (bid & 7) * 32 + (bid >> 3);
    const int brow = (swz >> 4) * 256, bcol = (swz & 15) * 256;

    // staging: chunk = 64 rows x 64 cols; wave w rows [8w,8w+8); source granule
    // permuted by the T2 involution so linear LDS write leaves
    // LDS[R][cb] = global[cb ^ ((R&7)<<4)].
    const int srow = w * 8 + (lane >> 3);
    const int scol = ((lane & 7) ^ (lane >> 3)) * 8;

    f32x4 acc[8][4] = {};

    // prologue: stage tile 0 in deadline order; keep A1,A3 (ph3 data) in flight
    STAGE_B(0, 0, 0); STAGE_B(0, 1, 0); STAGE_B(0, 2, 0); STAGE_B(0, 3, 0);
    STAGE_A(0, 0, 0); STAGE_A(0, 2, 0); STAGE_A(0, 1, 0); STAGE_A(0, 3, 0);
    asm volatile("s_waitcnt vmcnt(2)" ::: "memory");
    BAR();

#pragma unroll 1
    for (int tp = 0; tp < NT; tp += 2) {
        k_tile<0>(tp,     As, Bs, acc, A, B, brow, bcol, srow, scol, w, wr, wc, l15, lhi, swz8);
        k_tile<1>(tp + 1, As, Bs, acc, A, B, brow, bcol, srow, scol, w, wr, wc, l15, lhi, swz8);
    }

    // ---- fused epilogue: dist = sqrt(max(s1 + s2 - 2*dot, EPS)); masked max/min ----
    int   tcol[4];
    float s2c[4];
#pragma unroll
    for (int n = 0; n < 4; ++n) {
        int col = bcol + wc * 64 + n * 16 + l15;
        tcol[n] = tgt[col];
        s2c[n]  = sq2[col];
    }
    const float INF = __uint_as_float(0x7f800000u);
#pragma unroll
    for (int m = 0; m < 8; ++m) {
#pragma unroll
        for (int reg = 0; reg < 4; ++reg) {
            // C/D layout (m89-verified): col = lane&15, row = (lane>>4)*4 + reg
            int   row  = brow + wr * 128 + m * 16 + lhi * 4 + reg;
            int   trow = tgt[row];
            float s1   = sq1[row];
            float pmax = 0.0f;
            float nmin = INF;
#pragma unroll
            for (int n = 0; n < 4; ++n) {
                float d2 = s1 + s2c[n] - 2.0f * acc[m][n][reg];
                float dd = sqrtf(fmaxf(d2, EPSF));
                if (trow == tcol[n]) pmax = fmaxf(pmax, dd);
                else                 nmin = fminf(nmin, dd);
            }
#pragma unroll
            for (int s = 1; s < 16; s <<= 1) {
                pmax = fmaxf(pmax, __shfl_xor(pmax, s));
                nmin = fminf(nmin, __shfl_xor(nmin, s));
            }
            if (l15 == 0) {
                atomicMax(&ap_bits[row], __float_as_uint(pmax));
                atomicMin(&an_bits[row], __float_as_uint(nmin));
            }
        }
    }
}

// ---------------------------------------------------------------------------
// Kernel 3: loss = mean(relu(ap - an + margin)); prec = mean(an > ap)
// ---------------------------------------------------------------------------
__global__ __launch_bounds__(256) void finalize_kernel(
    const unsigned* __restrict__ ap_bits, const unsigned* __restrict__ an_bits,
    const float* __restrict__ marginp, float* __restrict__ out) {
    const int tid = threadIdx.x;
    const float margin = marginp[0];
    float ls = 0.f, ps = 0.f;
    for (int i = tid; i < N_ROWS; i += 256) {
        float a = __uint_as_float(ap_bits[i]);
        float b = __uint_as_float(an_bits[i]);
        ls += fmaxf(a - b + margin, 0.0f);
        ps += (b > a) ? 1.0f : 0.0f;
    }
    for (int s = 32; s > 0; s >>= 1) {
        ls += __shfl_down(ls, s);
        ps += __shfl_down(ps, s);
    }
    __shared__ float sl[4], sp[4];
    if ((tid & 63) == 0) { sl[tid >> 6] = ls; sp[tid >> 6] = ps; }
    __syncthreads();
    if (tid == 0) {
        ls = sl[0] + sl[1] + sl[2] + sl[3];
        ps = sp[0] + sp[1] + sp[2] + sp[3];
        out[0] = ls / (float)N_ROWS;
        out[1] = ps / (float)N_ROWS;
    }
}

// ---------------------------------------------------------------------------
extern "C" void kernel_launch(void* const* d_in, const int* in_sizes, int n_in,
                              void* d_out, int out_size, void* d_ws, size_t ws_size,
                              hipStream_t stream) {
    const float* m1  = (const float*)d_in[0];
    const float* m2  = (const float*)d_in[1];
    const int*   tgt = (const int*)d_in[2];
    const float* mrg = (const float*)d_in[3];

    char* ws = (char*)d_ws;
    unsigned short* abf = (unsigned short*)ws;                         // 16 MB bf16 modal1
    unsigned short* bbf = (unsigned short*)(ws + 16777216);            // 16 MB bf16 modal2
    float*    sq1 = (float*)(ws + 33554432);
    float*    sq2 = (float*)(ws + 33554432 + 16384);
    unsigned* ap  = (unsigned*)(ws + 33554432 + 32768);
    unsigned* an  = (unsigned*)(ws + 33554432 + 49152);

    float* outp = (float*)d_out;

    prep_kernel<<<2 * N_ROWS / 4, 256, 0, stream>>>(m1, m2, abf, bbf, sq1, sq2, ap, an);
    dim3 grid(N_ROWS / 256, N_ROWS / 256);
    dist_gemm_kernel<<<grid, 512, 0, stream>>>(abf, bbf, sq1, sq2, tgt, ap, an);
    finalize_kernel<<<1, 256, 0, stream>>>(ap, an, mrg, outp);
}

// Round 15
// 187.122 us; speedup vs baseline: 1.0102x; 1.0102x over previous
//
#include <hip/hip_runtime.h>
#include <hip/hip_bf16.h>
#include <stdint.h>

#define N_ROWS 4096
#define DIM    2048
#define NT     (DIM / 64)   // 32 K-tiles of BK=64
#define EPSF   1e-12f

typedef __bf16 bf16x8 __attribute__((ext_vector_type(8)));
typedef float  f32x4  __attribute__((ext_vector_type(4)));

typedef __attribute__((address_space(1))) void gv_t;
typedef __attribute__((address_space(3))) void lv_t;

__device__ __forceinline__ void gload_lds16(const void* g, void* l) {
    // async global->LDS, 16B/lane; LDS dest = wave-uniform base + lane*16
    __builtin_amdgcn_global_load_lds((gv_t*)g, (lv_t*)l, 16, 0, 0);
}

// round-to-nearest-even f32 -> bf16 bits
__device__ __forceinline__ unsigned f2bf(float f) {
    unsigned u = __float_as_uint(f);
    return (u + 0x7FFFu + ((u >> 16) & 1u)) >> 16;
}

// ---------------------------------------------------------------------------
// Kernel 1: f32 -> bf16 convert, row sum-of-squares, init per-row atoms.
// Wave-per-row: 2048 blocks x 4 waves; pure shfl reduce, no LDS/syncthreads.
// ---------------------------------------------------------------------------
__global__ __launch_bounds__(256) void prep_kernel(
    const float* __restrict__ m1, const float* __restrict__ m2,
    unsigned short* __restrict__ abf, unsigned short* __restrict__ bbf,
    float* __restrict__ sq1, float* __restrict__ sq2,
    unsigned* __restrict__ ap_bits, unsigned* __restrict__ an_bits) {
    const int w    = threadIdx.x >> 6;
    const int lane = threadIdx.x & 63;
    const int r_all = blockIdx.x * 4 + w;        // 0..8191
    const bool isB = r_all >= N_ROWS;
    const int r = isB ? r_all - N_ROWS : r_all;
    const float* src = (isB ? m2 : m1) + (size_t)r * DIM;
    unsigned short* dst = (isB ? bbf : abf) + (size_t)r * DIM;

    const float4* s4 = (const float4*)src;       // 512 float4 per row
    float acc = 0.f;
#pragma unroll
    for (int k = 0; k < 8; ++k) {
        float4 v = s4[lane + 64 * k];
        acc += v.x*v.x + v.y*v.y + v.z*v.z + v.w*v.w;
        uint2 p;
        p.x = f2bf(v.x) | (f2bf(v.y) << 16);
        p.y = f2bf(v.z) | (f2bf(v.w) << 16);
        *(uint2*)(dst + (lane + 64 * k) * 4) = p;
    }
    for (int s = 32; s > 0; s >>= 1) acc += __shfl_down(acc, s);
    if (lane == 0) {
        (isB ? sq2 : sq1)[r] = acc;
        if (!isB) {
            ap_bits[r] = 0u;           // dist > 0, so 0.0f works as -inf for max
            an_bits[r] = 0x7f800000u;  // +inf
        }
    }
}

// ---------------------------------------------------------------------------
// Kernel 2: fused bf16 MFMA GEMM (A·B^T) + distance + masked max/min + atomics.
// 8-phase counted-vmcnt (T3+T4+T5+T1) + T2 XOR-swizzle (r13: conflicts=0).
// Round-15 change: DEEPENED stage schedule. ph1(t+1) consumes {B0-3,A0,A2};
// previously A0,A2 were issued at ph3(t) (1 phase before the ph4 wait ->
// ~300cy stall/tile). Now: ph1(t) issues B0,B1,A0,A2(t+1); ph2 issues B2,B3;
// ph3 issues A1,A3. Every waited load is >=2 phases (~1200cy) old.
// Ledger: ph2 vmcnt(6) retires A1,A3(t) (read ph3); ph4 vmcnt(2) retires
// B0-3,A0,A2(t+1) (read ph1(t+1)); never 0 in main loop. Runtime-cur loop
// (round-14 template unroll regressed; reverted).
// ---------------------------------------------------------------------------
__global__ __launch_bounds__(512) void dist_gemm_kernel(
    const unsigned short* __restrict__ A, const unsigned short* __restrict__ B,
    const float* __restrict__ sq1, const float* __restrict__ sq2,
    const int* __restrict__ tgt,
    unsigned* __restrict__ ap_bits, unsigned* __restrict__ an_bits) {
    __shared__ unsigned short As[2][256 * 64];   // 64 KB
    __shared__ unsigned short Bs[2][256 * 64];   // 64 KB

    const int tid  = threadIdx.x;
    const int w    = tid >> 6;            // wave 0..7
    const int lane = tid & 63;
    const int wr   = w >> 2, wc = w & 3;  // wave grid 2x4; wave owns 128x64 of C
    const int l15  = lane & 15, lhi = lane >> 4;
    const int swz8 = (l15 & 7) * 8;       // read-side XOR key (elements)

    // bijective XCD swizzle over the 16x16 grid (256 blocks, 256 % 8 == 0)
    const int bid  = blockIdx.y * 16 + blockIdx.x;
    const int swz  = (bid & 7) * 32 + (bid >> 3);
    const int brow = (swz >> 4) * 256, bcol = (swz & 15) * 256;

    // staging: chunk = 64 rows x 64 cols; wave w rows [8w,8w+8); source granule
    // permuted by the T2 involution so the linear LDS write leaves
    // LDS[R][cb] = global[cb ^ ((R&7)<<4)].
    const int srow = w * 8 + (lane >> 3);
    const int scol = ((lane & 7) ^ (lane >> 3)) * 8;

#define STAGE_A(buf, c, kt1) gload_lds16(                                        \
        A + (size_t)(brow + (c) * 64 + srow) * DIM + (kt1) + scol,               \
        &As[buf][((c) * 64 + w * 8) * 64])
#define STAGE_B(buf, c, kt1) gload_lds16(                                        \
        B + (size_t)(bcol + (c) * 64 + srow) * DIM + (kt1) + scol,               \
        &Bs[buf][((c) * 64 + w * 8) * 64])
// read with the same XOR: R&7 == l15&7 for both A (R=wr*128+m*16+l15) and B
#define LDA(m, kk) (*(const bf16x8*)&As[cur][(wr * 128 + (m) * 16 + l15) * 64 + (((kk) * 32 + lhi * 8) ^ swz8)])
#define LDB(n, kk) (*(const bf16x8*)&Bs[cur][(wc * 64 + (n) * 16 + l15) * 64 + (((kk) * 32 + lhi * 8) ^ swz8)])
#define BAR() asm volatile("s_barrier" ::: "memory")
#define MFMA(a, b, c) __builtin_amdgcn_mfma_f32_16x16x32_bf16((a), (b), (c), 0, 0, 0)

    f32x4 acc[8][4] = {};

    // prologue: stage tile 0 in deadline order (ph1-needs first, A1,A3 last);
    // vmcnt(2) keeps A1,A3 (ph3 data) in flight
    STAGE_B(0, 0, 0); STAGE_B(0, 1, 0); STAGE_A(0, 0, 0); STAGE_A(0, 2, 0);
    STAGE_B(0, 2, 0); STAGE_B(0, 3, 0); STAGE_A(0, 1, 0); STAGE_A(0, 3, 0);
    asm volatile("s_waitcnt vmcnt(2)" ::: "memory");
    BAR();

    for (int t = 0; t < NT; ++t) {
        const int  cur  = t & 1, nxt = cur ^ 1;
        const int  kt1  = (t + 1) * 64;
        const bool more = (t + 1 < NT);
        bf16x8 af[4][2], bn[4][2];

        // ---- phase 1: A rows m0-3 + B cols n0-1; stage next B0,B1,A0,A2 ----
#pragma unroll
        for (int m = 0; m < 4; ++m) { af[m][0] = LDA(m, 0); af[m][1] = LDA(m, 1); }
#pragma unroll
        for (int n = 0; n < 2; ++n) { bn[n][0] = LDB(n, 0); bn[n][1] = LDB(n, 1); }
        if (more) { STAGE_B(nxt, 0, kt1); STAGE_B(nxt, 1, kt1);
                    STAGE_A(nxt, 0, kt1); STAGE_A(nxt, 2, kt1); }
        BAR();
        __builtin_amdgcn_s_setprio(1);
#pragma unroll
        for (int m = 0; m < 4; ++m)
#pragma unroll
            for (int n = 0; n < 2; ++n) {
                acc[m][n] = MFMA(af[m][0], bn[n][0], acc[m][n]);
                acc[m][n] = MFMA(af[m][1], bn[n][1], acc[m][n]);
            }
        __builtin_amdgcn_s_setprio(0);
        BAR();

        // ---- phase 2: B cols n2-3; stage next B2,B3; retire this tile's A1,A3 ----
#pragma unroll
        for (int n = 0; n < 2; ++n) { bn[n + 2][0] = LDB(n + 2, 0); bn[n + 2][1] = LDB(n + 2, 1); }
        if (more) { STAGE_B(nxt, 2, kt1); STAGE_B(nxt, 3, kt1); }
        if (t == NT - 1) { asm volatile("s_waitcnt vmcnt(0)" ::: "memory"); }
        else             { asm volatile("s_waitcnt vmcnt(6)" ::: "memory"); }  // A1,A3(t) landed (issued ph3(t-1))
        BAR();
        __builtin_amdgcn_s_setprio(1);
#pragma unroll
        for (int m = 0; m < 4; ++m)
#pragma unroll
            for (int n = 0; n < 2; ++n) {
                acc[m][n + 2] = MFMA(af[m][0], bn[n + 2][0], acc[m][n + 2]);
                acc[m][n + 2] = MFMA(af[m][1], bn[n + 2][1], acc[m][n + 2]);
            }
        __builtin_amdgcn_s_setprio(0);
        BAR();

        // ---- phase 3: A rows m4-7; stage next A1,A3 ----
#pragma unroll
        for (int m = 0; m < 4; ++m) { af[m][0] = LDA(m + 4, 0); af[m][1] = LDA(m + 4, 1); }
        if (more) { STAGE_A(nxt, 1, kt1); STAGE_A(nxt, 3, kt1); }
        BAR();
        __builtin_amdgcn_s_setprio(1);
#pragma unroll
        for (int m = 0; m < 4; ++m)
#pragma unroll
            for (int n = 0; n < 2; ++n) {
                acc[m + 4][n] = MFMA(af[m][0], bn[n][0], acc[m + 4][n]);
                acc[m + 4][n] = MFMA(af[m][1], bn[n][1], acc[m + 4][n]);
            }
        __builtin_amdgcn_s_setprio(0);
        BAR();

        // ---- phase 4: no reads/stages; retire next tile's ph1 set ----
        if (more) {
            asm volatile("s_waitcnt vmcnt(2)" ::: "memory");  // B0-3,A0,A2(t+1) landed (issued ph1/ph2, >=2 phases ago)
        }
        BAR();
        __builtin_amdgcn_s_setprio(1);
#pragma unroll
        for (int m = 0; m < 4; ++m)
#pragma unroll
            for (int n = 0; n < 2; ++n) {
                acc[m + 4][n + 2] = MFMA(af[m][0], bn[n + 2][0], acc[m + 4][n + 2]);
                acc[m + 4][n + 2] = MFMA(af[m][1], bn[n + 2][1], acc[m + 4][n + 2]);
            }
        __builtin_amdgcn_s_setprio(0);
        BAR();
    }

    // ---- fused epilogue: dist = sqrt(max(s1 + s2 - 2*dot, EPS)); masked max/min ----
    int   tcol[4];
    float s2c[4];
#pragma unroll
    for (int n = 0; n < 4; ++n) {
        int col = bcol + wc * 64 + n * 16 + l15;
        tcol[n] = tgt[col];
        s2c[n]  = sq2[col];
    }
    const float INF = __uint_as_float(0x7f800000u);
#pragma unroll
    for (int m = 0; m < 8; ++m) {
#pragma unroll
        for (int reg = 0; reg < 4; ++reg) {
            // C/D layout (m89-verified): col = lane&15, row = (lane>>4)*4 + reg
            int   row  = brow + wr * 128 + m * 16 + lhi * 4 + reg;
            int   trow = tgt[row];
            float s1   = sq1[row];
            float pmax = 0.0f;
            float nmin = INF;
#pragma unroll
            for (int n = 0; n < 4; ++n) {
                float d2 = s1 + s2c[n] - 2.0f * acc[m][n][reg];
                float dd = sqrtf(fmaxf(d2, EPSF));
                if (trow == tcol[n]) pmax = fmaxf(pmax, dd);
                else                 nmin = fminf(nmin, dd);
            }
#pragma unroll
            for (int s = 1; s < 16; s <<= 1) {
                pmax = fmaxf(pmax, __shfl_xor(pmax, s));
                nmin = fminf(nmin, __shfl_xor(nmin, s));
            }
            if (l15 == 0) {
                atomicMax(&ap_bits[row], __float_as_uint(pmax));
                atomicMin(&an_bits[row], __float_as_uint(nmin));
            }
        }
    }
#undef STAGE_A
#undef STAGE_B
#undef LDA
#undef LDB
#undef BAR
#undef MFMA
}

// ---------------------------------------------------------------------------
// Kernel 3: loss = mean(relu(ap - an + margin)); prec = mean(an > ap)
// ---------------------------------------------------------------------------
__global__ __launch_bounds__(256) void finalize_kernel(
    const unsigned* __restrict__ ap_bits, const unsigned* __restrict__ an_bits,
    const float* __restrict__ marginp, float* __restrict__ out) {
    const int tid = threadIdx.x;
    const float margin = marginp[0];
    float ls = 0.f, ps = 0.f;
    for (int i = tid; i < N_ROWS; i += 256) {
        float a = __uint_as_float(ap_bits[i]);
        float b = __uint_as_float(an_bits[i]);
        ls += fmaxf(a - b + margin, 0.0f);
        ps += (b > a) ? 1.0f : 0.0f;
    }
    for (int s = 32; s > 0; s >>= 1) {
        ls += __shfl_down(ls, s);
        ps += __shfl_down(ps, s);
    }
    __shared__ float sl[4], sp[4];
    if ((tid & 63) == 0) { sl[tid >> 6] = ls; sp[tid >> 6] = ps; }
    __syncthreads();
    if (tid == 0) {
        ls = sl[0] + sl[1] + sl[2] + sl[3];
        ps = sp[0] + sp[1] + sp[2] + sp[3];
        out[0] = ls / (float)N_ROWS;
        out[1] = ps / (float)N_ROWS;
    }
}

// ---------------------------------------------------------------------------
extern "C" void kernel_launch(void* const* d_in, const int* in_sizes, int n_in,
                              void* d_out, int out_size, void* d_ws, size_t ws_size,
                              hipStream_t stream) {
    const float* m1  = (const float*)d_in[0];
    const float* m2  = (const float*)d_in[1];
    const int*   tgt = (const int*)d_in[2];
    const float* mrg = (const float*)d_in[3];

    char* ws = (char*)d_ws;
    unsigned short* abf = (unsigned short*)ws;                         // 16 MB bf16 modal1
    unsigned short* bbf = (unsigned short*)(ws + 16777216);            // 16 MB bf16 modal2
    float*    sq1 = (float*)(ws + 33554432);
    float*    sq2 = (float*)(ws + 33554432 + 16384);
    unsigned* ap  = (unsigned*)(ws + 33554432 + 32768);
    unsigned* an  = (unsigned*)(ws + 33554432 + 49152);

    float* outp = (float*)d_out;

    prep_kernel<<<2 * N_ROWS / 4, 256, 0, stream>>>(m1, m2, abf, bbf, sq1, sq2, ap, an);
    dim3 grid(N_ROWS / 256, N_ROWS / 256);
    dist_gemm_kernel<<<grid, 512, 0, stream>>>(abf, bbf, sq1, sq2, tgt, ap, an);
    finalize_kernel<<<1, 256, 0, stream>>>(ap, an, mrg, outp);
}